// Round 4
// baseline (263.247 us; speedup 1.0000x reference)
//
#include <hip/hip_runtime.h>

// YOLO v1 loss. pred/target: (16384, 7, 7, 30) fp32.
// R4: no LDS. Two adjacent cells = 240 B = 15 aligned float4 per input.
// Each lane loads 15 float4 of targ + 15 of pred (fully coalesced streaming,
// adjacent lanes = adjacent 240-B chunks), computes both cells' losses from
// registers. No stage->drain->die: compiler interleaves loads/compute with
// fine-grained vmcnt waits; ~12 waves/CU x 30 KB outstanding saturates HBM.

#define CH 30

__device__ __forceinline__ float cell_loss(const float* __restrict__ t,
                                           const float* __restrict__ p) {
    const float t4 = t[4];
    const bool coo = t4 > 0.0f;

    // no-object loss (weight 0.5)
    const float d4 = p[4] - t4;
    const float d9 = p[9] - t[9];
    float sum = coo ? 0.0f : 0.5f * (d4 * d4 + d9 * d9);

    if (coo) {
        // class loss (channels 10..29)
        float cl = 0.0f;
#pragma unroll
        for (int c = 10; c < 30; ++c) {
            const float d = p[c] - t[c];
            cl += d * d;
        }
        sum += cl;

        // target box 0 corners (reference's exact math incl. inverted inter)
        const float tltx = t[0] - 0.5f * t[2];
        const float tlty = t[1] - 0.5f * t[3];
        const float trbx = t[0] + 0.5f * t[2];
        const float trby = t[1] + 0.5f * t[3];
        const float area2 = (trbx - tltx) * (trby - tlty);

        float iou0, iou1;
#pragma unroll
        for (int b = 0; b < 2; ++b) {
            const float bx = p[b * 5 + 0], by = p[b * 5 + 1];
            const float bw = p[b * 5 + 2], bh = p[b * 5 + 3];
            const float pltx = bx - 0.5f * bw, plty = by - 0.5f * bh;
            const float prbx = bx + 0.5f * bw, prby = by + 0.5f * bh;
            const float ltx = fmaxf(pltx, tltx), lty = fmaxf(plty, tlty);
            const float rbx = fminf(prbx, trbx), rby = fminf(prby, trby);
            const float inter = ((rbx - ltx < 0.0f) ? 1.0f : 0.0f) *
                                ((rby - lty < 0.0f) ? 1.0f : 0.0f);
            const float area1 = (prbx - pltx) * (prby - plty);
            const float iou = inter / (area1 + area2 - inter);
            if (b == 0) iou0 = iou; else iou1 = iou;
        }
        // jnp.argmax first-index tie-break: idx=1 only if strictly greater
        const int o = (iou1 > iou0) ? 5 : 0;

        // contain loss (weight 1)
        const float dc = p[o + 4] - t[o + 4];
        sum += dc * dc;

        // localization loss (weight 5)
        const float dx = p[o + 0] - t[o + 0];
        const float dy = p[o + 1] - t[o + 1];
        const float dw = sqrtf(p[o + 2]) - sqrtf(t[o + 2]);
        const float dh = sqrtf(p[o + 3]) - sqrtf(t[o + 3]);
        sum += 5.0f * (dx * dx + dy * dy + dw * dw + dh * dh);
    }
    return sum;
}

__global__ __launch_bounds__(256, 3)
void yolo_partial(const float* __restrict__ pred,
                  const float* __restrict__ targ,
                  float* __restrict__ partial) {
    __shared__ float wave_sums[4];

    const int tid = threadIdx.x;
    const long long pair = (long long)blockIdx.x * 256 + tid;  // 0..401407

    const float4* t4 = (const float4*)targ + pair * 15;
    const float4* p4 = (const float4*)pred + pair * 15;

    float tv[60], pv[60];
#pragma unroll
    for (int i = 0; i < 15; ++i) {
        const float4 v = t4[i];
        tv[4 * i + 0] = v.x; tv[4 * i + 1] = v.y;
        tv[4 * i + 2] = v.z; tv[4 * i + 3] = v.w;
    }
#pragma unroll
    for (int i = 0; i < 15; ++i) {
        const float4 v = p4[i];
        pv[4 * i + 0] = v.x; pv[4 * i + 1] = v.y;
        pv[4 * i + 2] = v.z; pv[4 * i + 3] = v.w;
    }

    float sum = cell_loss(tv, pv) + cell_loss(tv + CH, pv + CH);

    // wave shuffle reduce, then block reduce
#pragma unroll
    for (int off = 32; off > 0; off >>= 1)
        sum += __shfl_down(sum, off, 64);
    const int wave = tid >> 6;
    const int lane = tid & 63;
    if (lane == 0) wave_sums[wave] = sum;
    __syncthreads();
    if (tid == 0) {
        partial[blockIdx.x] = (wave_sums[0] + wave_sums[1]) +
                              (wave_sums[2] + wave_sums[3]);
    }
}

__global__ __launch_bounds__(256)
void yolo_reduce(const float* __restrict__ partial, int n, float* __restrict__ out) {
    __shared__ float wave_sums[4];
    float s = 0.0f;
    const int n4 = n >> 2;
    const float4* p4 = (const float4*)partial;
    for (int v = threadIdx.x; v < n4; v += 256) {
        const float4 x = p4[v];
        s += (x.x + x.y) + (x.z + x.w);
    }
    for (int v = (n4 << 2) + threadIdx.x; v < n; v += 256)
        s += partial[v];
#pragma unroll
    for (int off = 32; off > 0; off >>= 1)
        s += __shfl_down(s, off, 64);
    const int wave = threadIdx.x >> 6;
    const int lane = threadIdx.x & 63;
    if (lane == 0) wave_sums[wave] = s;
    __syncthreads();
    if (threadIdx.x == 0) {
        const float tot = wave_sums[0] + wave_sums[1] + wave_sums[2] + wave_sums[3];
        out[0] = tot * (1.0f / 16384.0f);
    }
}

extern "C" void kernel_launch(void* const* d_in, const int* in_sizes, int n_in,
                              void* d_out, int out_size, void* d_ws, size_t ws_size,
                              hipStream_t stream) {
    const float* pred = (const float*)d_in[0];
    const float* targ = (const float*)d_in[1];
    float* out = (float*)d_out;
    float* partial = (float*)d_ws;

    const int n_cells = in_sizes[0] / CH;     // 802816
    const int n_pairs = n_cells / 2;          // 401408
    const int blocks = n_pairs / 256;         // 1568

    yolo_partial<<<blocks, 256, 0, stream>>>(pred, targ, partial);
    yolo_reduce<<<1, 256, 0, stream>>>(partial, blocks, out);
}

// Round 5
// 209.705 us; speedup vs baseline: 1.2553x; 1.2553x over previous
//
#include <hip/hip_runtime.h>

// YOLO v1 loss. pred/target: (16384, 7, 7, 30) fp32.
// R5: R4's LDS-free streaming structure (two adjacent cells = 240 B = 15
// aligned float4 per input per lane) with ALL array indices compile-time
// constant (template<int B> + static ?: selects) so SROA keeps tv/pv in
// VGPRs. R4's runtime-indexed p[o+4] forced both arrays to scratch ->
// 380 MB of spill traffic; this removes it.

#define CH 30

template<int B>
__device__ __forceinline__ float cell_loss(const float (&t)[60], const float (&p)[60]) {
    const float t4 = t[B + 4];
    const bool coo = t4 > 0.0f;

    // no-object loss (weight 0.5)
    const float d4 = p[B + 4] - t4;
    const float d9 = p[B + 9] - t[B + 9];
    float sum = coo ? 0.0f : 0.5f * (d4 * d4 + d9 * d9);

    if (coo) {
        // class loss (channels 10..29) — unrolled, constant indices
        float cl = 0.0f;
#pragma unroll
        for (int c = 10; c < 30; ++c) {
            const float d = p[B + c] - t[B + c];
            cl += d * d;
        }
        sum += cl;

        // target box 0 corners (reference's exact math incl. inverted inter)
        const float tltx = t[B + 0] - 0.5f * t[B + 2];
        const float tlty = t[B + 1] - 0.5f * t[B + 3];
        const float trbx = t[B + 0] + 0.5f * t[B + 2];
        const float trby = t[B + 1] + 0.5f * t[B + 3];
        const float area2 = (trbx - tltx) * (trby - tlty);

        float iou0, iou1;
#pragma unroll
        for (int b = 0; b < 2; ++b) {
            const float bx = p[B + b * 5 + 0], by = p[B + b * 5 + 1];
            const float bw = p[B + b * 5 + 2], bh = p[B + b * 5 + 3];
            const float pltx = bx - 0.5f * bw, plty = by - 0.5f * bh;
            const float prbx = bx + 0.5f * bw, prby = by + 0.5f * bh;
            const float ltx = fmaxf(pltx, tltx), lty = fmaxf(plty, tlty);
            const float rbx = fminf(prbx, trbx), rby = fminf(prby, trby);
            const float inter = ((rbx - ltx < 0.0f) ? 1.0f : 0.0f) *
                                ((rby - lty < 0.0f) ? 1.0f : 0.0f);
            const float area1 = (prbx - pltx) * (prby - plty);
            const float iou = inter / (area1 + area2 - inter);
            if (b == 0) iou0 = iou; else iou1 = iou;
        }
        // jnp.argmax first-index tie-break: idx=1 only if strictly greater
        const bool idx1 = iou1 > iou0;

        // responsible boxes via STATIC selects (constant indices only)
        const float rpx = idx1 ? p[B + 5] : p[B + 0];
        const float rpy = idx1 ? p[B + 6] : p[B + 1];
        const float rpw = idx1 ? p[B + 7] : p[B + 2];
        const float rph = idx1 ? p[B + 8] : p[B + 3];
        const float rpc = idx1 ? p[B + 9] : p[B + 4];
        const float rtx = idx1 ? t[B + 5] : t[B + 0];
        const float rty = idx1 ? t[B + 6] : t[B + 1];
        const float rtw = idx1 ? t[B + 7] : t[B + 2];
        const float rth = idx1 ? t[B + 8] : t[B + 3];
        const float rtc = idx1 ? t[B + 9] : t[B + 4];

        // contain loss (weight 1)
        const float dc = rpc - rtc;
        sum += dc * dc;

        // localization loss (weight 5)
        const float dx = rpx - rtx;
        const float dy = rpy - rty;
        const float dw = sqrtf(rpw) - sqrtf(rtw);
        const float dh = sqrtf(rph) - sqrtf(rth);
        sum += 5.0f * (dx * dx + dy * dy + dw * dw + dh * dh);
    }
    return sum;
}

__global__ __launch_bounds__(256, 3)
void yolo_partial(const float* __restrict__ pred,
                  const float* __restrict__ targ,
                  float* __restrict__ partial) {
    __shared__ float wave_sums[4];

    const int tid = threadIdx.x;
    const long long pair = (long long)blockIdx.x * 256 + tid;  // 0..401407

    const float4* t4 = (const float4*)targ + pair * 15;
    const float4* p4 = (const float4*)pred + pair * 15;

    float tv[60], pv[60];
#pragma unroll
    for (int i = 0; i < 15; ++i) {
        const float4 v = t4[i];
        tv[4 * i + 0] = v.x; tv[4 * i + 1] = v.y;
        tv[4 * i + 2] = v.z; tv[4 * i + 3] = v.w;
    }
#pragma unroll
    for (int i = 0; i < 15; ++i) {
        const float4 v = p4[i];
        pv[4 * i + 0] = v.x; pv[4 * i + 1] = v.y;
        pv[4 * i + 2] = v.z; pv[4 * i + 3] = v.w;
    }

    float sum = cell_loss<0>(tv, pv) + cell_loss<CH>(tv, pv);

    // wave shuffle reduce, then block reduce
#pragma unroll
    for (int off = 32; off > 0; off >>= 1)
        sum += __shfl_down(sum, off, 64);
    const int wave = tid >> 6;
    const int lane = tid & 63;
    if (lane == 0) wave_sums[wave] = sum;
    __syncthreads();
    if (tid == 0) {
        partial[blockIdx.x] = (wave_sums[0] + wave_sums[1]) +
                              (wave_sums[2] + wave_sums[3]);
    }
}

__global__ __launch_bounds__(256)
void yolo_reduce(const float* __restrict__ partial, int n, float* __restrict__ out) {
    __shared__ float wave_sums[4];
    float s = 0.0f;
    const int n4 = n >> 2;
    const float4* p4 = (const float4*)partial;
    for (int v = threadIdx.x; v < n4; v += 256) {
        const float4 x = p4[v];
        s += (x.x + x.y) + (x.z + x.w);
    }
    for (int v = (n4 << 2) + threadIdx.x; v < n; v += 256)
        s += partial[v];
#pragma unroll
    for (int off = 32; off > 0; off >>= 1)
        s += __shfl_down(s, off, 64);
    const int wave = threadIdx.x >> 6;
    const int lane = threadIdx.x & 63;
    if (lane == 0) wave_sums[wave] = s;
    __syncthreads();
    if (threadIdx.x == 0) {
        const float tot = wave_sums[0] + wave_sums[1] + wave_sums[2] + wave_sums[3];
        out[0] = tot * (1.0f / 16384.0f);
    }
}

extern "C" void kernel_launch(void* const* d_in, const int* in_sizes, int n_in,
                              void* d_out, int out_size, void* d_ws, size_t ws_size,
                              hipStream_t stream) {
    const float* pred = (const float*)d_in[0];
    const float* targ = (const float*)d_in[1];
    float* out = (float*)d_out;
    float* partial = (float*)d_ws;

    const int n_cells = in_sizes[0] / CH;     // 802816
    const int n_pairs = n_cells / 2;          // 401408
    const int blocks = n_pairs / 256;         // 1568

    yolo_partial<<<blocks, 256, 0, stream>>>(pred, targ, partial);
    yolo_reduce<<<1, 256, 0, stream>>>(partial, blocks, out);
}

// Round 6
// 208.474 us; speedup vs baseline: 1.2627x; 1.0059x over previous
//
#include <hip/hip_runtime.h>

// YOLO v1 loss. pred/target: (16384, 7, 7, 30) fp32.
// R6: register double-buffered software pipeline with persistent waves.
//   One cell per lane per stage (30 floats/tensor = 15 float2 each).
//   Two register cell-buffers A/B: loads for stage k+1 issue BEFORE stage k
//   is consumed -> compiler emits fine-grained vmcnt(N) (never a full drain),
//   keeping ~15 KB/wave continuously in flight x 12 waves/CU.
//   Grid = 768 blocks = exactly 3 resident blocks/CU (no churn, no tail):
//   196608 lanes x 4 full stages + guarded 5th stage (first 16384 lanes).

#define CH 30
#define LANES_TOTAL 196608            // 768 blocks * 256 threads
#define N_CELLS 802816

struct Cell {
    float2 t[15];
    float2 p[15];
};

__device__ __forceinline__ void load_cell(Cell& c,
                                          const float* __restrict__ targ,
                                          const float* __restrict__ pred,
                                          long long cell) {
    const float2* tb = (const float2*)targ + cell * 15;
    const float2* pb = (const float2*)pred + cell * 15;
#pragma unroll
    for (int i = 0; i < 15; ++i) c.t[i] = tb[i];
#pragma unroll
    for (int i = 0; i < 15; ++i) c.p[i] = pb[i];
}

__device__ __forceinline__ float cell_loss(const Cell& c) {
    const float2 t01 = c.t[0], t23 = c.t[1], t45 = c.t[2], t67 = c.t[3], t89 = c.t[4];
    const float2 p01 = c.p[0], p23 = c.p[1], p45 = c.p[2], p67 = c.p[3], p89 = c.p[4];

    const float t4 = t45.x;
    const bool coo = t4 > 0.0f;

    // no-object loss (weight 0.5)
    const float d4 = p45.x - t4;
    const float d9 = p89.y - t89.y;
    float sum = coo ? 0.0f : 0.5f * (d4 * d4 + d9 * d9);

    if (coo) {
        // class loss (channels 10..29)
        float cl = 0.0f;
#pragma unroll
        for (int k = 0; k < 10; ++k) {
            const float dx = c.p[5 + k].x - c.t[5 + k].x;
            const float dy = c.p[5 + k].y - c.t[5 + k].y;
            cl += dx * dx + dy * dy;
        }
        sum += cl;

        // target box 0 corners (reference's exact math incl. inverted inter)
        const float tltx = t01.x - 0.5f * t23.x;
        const float tlty = t01.y - 0.5f * t23.y;
        const float trbx = t01.x + 0.5f * t23.x;
        const float trby = t01.y + 0.5f * t23.y;
        const float area2 = (trbx - tltx) * (trby - tlty);

        // pred box 0: ch 0..4, pred box 1: ch 5..9
        const float b0x = p01.x, b0y = p01.y, b0w = p23.x, b0h = p23.y;
        const float b1x = p45.y, b1y = p67.x, b1w = p67.y, b1h = p89.x;

        float iou0, iou1;
        {
            const float pltx = b0x - 0.5f * b0w, plty = b0y - 0.5f * b0h;
            const float prbx = b0x + 0.5f * b0w, prby = b0y + 0.5f * b0h;
            const float ltx = fmaxf(pltx, tltx), lty = fmaxf(plty, tlty);
            const float rbx = fminf(prbx, trbx), rby = fminf(prby, trby);
            const float inter = ((rbx - ltx < 0.0f) ? 1.0f : 0.0f) *
                                ((rby - lty < 0.0f) ? 1.0f : 0.0f);
            const float area1 = (prbx - pltx) * (prby - plty);
            iou0 = inter / (area1 + area2 - inter);
        }
        {
            const float pltx = b1x - 0.5f * b1w, plty = b1y - 0.5f * b1h;
            const float prbx = b1x + 0.5f * b1w, prby = b1y + 0.5f * b1h;
            const float ltx = fmaxf(pltx, tltx), lty = fmaxf(plty, tlty);
            const float rbx = fminf(prbx, trbx), rby = fminf(prby, trby);
            const float inter = ((rbx - ltx < 0.0f) ? 1.0f : 0.0f) *
                                ((rby - lty < 0.0f) ? 1.0f : 0.0f);
            const float area1 = (prbx - pltx) * (prby - plty);
            iou1 = inter / (area1 + area2 - inter);
        }
        // jnp.argmax first-index tie-break: idx=1 only if strictly greater
        const bool idx1 = iou1 > iou0;

        const float rpx = idx1 ? b1x : b0x;
        const float rpy = idx1 ? b1y : b0y;
        const float rpw = idx1 ? b1w : b0w;
        const float rph = idx1 ? b1h : b0h;
        const float rpc = idx1 ? p89.y : p45.x;
        const float rtx = idx1 ? t45.y : t01.x;
        const float rty = idx1 ? t67.x : t01.y;
        const float rtw = idx1 ? t67.y : t23.x;
        const float rth = idx1 ? t89.x : t23.y;
        const float rtc = idx1 ? t89.y : t45.x;

        // contain loss (weight 1)
        const float dc = rpc - rtc;
        sum += dc * dc;

        // localization loss (weight 5)
        const float dx = rpx - rtx;
        const float dy = rpy - rty;
        const float dw = sqrtf(rpw) - sqrtf(rtw);
        const float dh = sqrtf(rph) - sqrtf(rth);
        sum += 5.0f * (dx * dx + dy * dy + dw * dw + dh * dh);
    }
    return sum;
}

__global__ __launch_bounds__(256, 3)
void yolo_partial(const float* __restrict__ pred,
                  const float* __restrict__ targ,
                  float* __restrict__ partial) {
    __shared__ float wave_sums[4];

    const int tid = threadIdx.x;
    const long long gid = (long long)blockIdx.x * 256 + tid;   // 0..196607
    const bool extra = gid < (N_CELLS - 4 * (long long)LANES_TOTAL);  // first 16384

    Cell A, B;
    float sum = 0.0f;

    // stage 0 loads
    load_cell(A, targ, pred, gid);
    // stage 1 loads in flight while consuming stage 0
    load_cell(B, targ, pred, gid + LANES_TOTAL);
    sum += cell_loss(A);
    // stage 2
    load_cell(A, targ, pred, gid + 2LL * LANES_TOTAL);
    sum += cell_loss(B);
    // stage 3
    load_cell(B, targ, pred, gid + 3LL * LANES_TOTAL);
    sum += cell_loss(A);
    // stage 4 (guarded; blocks 0-63 fully active, others fully skip)
    if (extra) load_cell(A, targ, pred, gid + 4LL * LANES_TOTAL);
    sum += cell_loss(B);
    if (extra) sum += cell_loss(A);

    // wave shuffle reduce, then block reduce
#pragma unroll
    for (int off = 32; off > 0; off >>= 1)
        sum += __shfl_down(sum, off, 64);
    const int wave = tid >> 6;
    const int lane = tid & 63;
    if (lane == 0) wave_sums[wave] = sum;
    __syncthreads();
    if (tid == 0) {
        partial[blockIdx.x] = (wave_sums[0] + wave_sums[1]) +
                              (wave_sums[2] + wave_sums[3]);
    }
}

__global__ __launch_bounds__(256)
void yolo_reduce(const float* __restrict__ partial, int n, float* __restrict__ out) {
    __shared__ float wave_sums[4];
    float s = 0.0f;
    const int n4 = n >> 2;
    const float4* p4 = (const float4*)partial;
    for (int v = threadIdx.x; v < n4; v += 256) {
        const float4 x = p4[v];
        s += (x.x + x.y) + (x.z + x.w);
    }
    for (int v = (n4 << 2) + threadIdx.x; v < n; v += 256)
        s += partial[v];
#pragma unroll
    for (int off = 32; off > 0; off >>= 1)
        s += __shfl_down(s, off, 64);
    const int wave = threadIdx.x >> 6;
    const int lane = threadIdx.x & 63;
    if (lane == 0) wave_sums[wave] = s;
    __syncthreads();
    if (threadIdx.x == 0) {
        const float tot = wave_sums[0] + wave_sums[1] + wave_sums[2] + wave_sums[3];
        out[0] = tot * (1.0f / 16384.0f);
    }
}

extern "C" void kernel_launch(void* const* d_in, const int* in_sizes, int n_in,
                              void* d_out, int out_size, void* d_ws, size_t ws_size,
                              hipStream_t stream) {
    const float* pred = (const float*)d_in[0];
    const float* targ = (const float*)d_in[1];
    float* out = (float*)d_out;
    float* partial = (float*)d_ws;

    const int blocks = LANES_TOTAL / 256;   // 768 = 3 resident blocks per CU

    yolo_partial<<<blocks, 256, 0, stream>>>(pred, targ, partial);
    yolo_reduce<<<1, 256, 0, stream>>>(partial, blocks, out);
}

// Round 7
// 205.934 us; speedup vs baseline: 1.2783x; 1.0123x over previous
//
#include <hip/hip_runtime.h>

// YOLO v1 loss. pred/target: (16384, 7, 7, 30) fp32.
// R7: R6's register double-buffered persistent pipeline, with compiler
// scheduling barriers (asm memory clobbers) pinning the memory-op order:
//   loadA, loadB, loadA', loadB', ... with compute slotted between.
// R6's pipeline was collapsed by the compiler (VGPR=80 -> loads sunk into
// uses, full drain each stage). The barriers force a real A/B buffer
// (~120 data VGPRs) and fine-grained vmcnt(N) waits: one full stage
// (~15 KB/wave) stays in flight while the previous stage is consumed.

#define CH 30
#define LANES_TOTAL 196608            // 768 blocks * 256 threads
#define N_CELLS 802816

#define SCHED_FENCE() asm volatile("" ::: "memory")

struct Cell {
    float2 t[15];
    float2 p[15];
};

__device__ __forceinline__ void load_cell(Cell& c,
                                          const float* __restrict__ targ,
                                          const float* __restrict__ pred,
                                          long long cell) {
    const float2* tb = (const float2*)targ + cell * 15;
    const float2* pb = (const float2*)pred + cell * 15;
#pragma unroll
    for (int i = 0; i < 15; ++i) c.t[i] = tb[i];
#pragma unroll
    for (int i = 0; i < 15; ++i) c.p[i] = pb[i];
}

__device__ __forceinline__ float cell_loss(const Cell& c) {
    const float2 t01 = c.t[0], t23 = c.t[1], t45 = c.t[2], t67 = c.t[3], t89 = c.t[4];
    const float2 p01 = c.p[0], p23 = c.p[1], p45 = c.p[2], p67 = c.p[3], p89 = c.p[4];

    const float t4 = t45.x;
    const bool coo = t4 > 0.0f;

    // no-object loss (weight 0.5)
    const float d4 = p45.x - t4;
    const float d9 = p89.y - t89.y;
    float sum = coo ? 0.0f : 0.5f * (d4 * d4 + d9 * d9);

    if (coo) {
        // class loss (channels 10..29)
        float cl = 0.0f;
#pragma unroll
        for (int k = 0; k < 10; ++k) {
            const float dx = c.p[5 + k].x - c.t[5 + k].x;
            const float dy = c.p[5 + k].y - c.t[5 + k].y;
            cl += dx * dx + dy * dy;
        }
        sum += cl;

        // target box 0 corners (reference's exact math incl. inverted inter)
        const float tltx = t01.x - 0.5f * t23.x;
        const float tlty = t01.y - 0.5f * t23.y;
        const float trbx = t01.x + 0.5f * t23.x;
        const float trby = t01.y + 0.5f * t23.y;
        const float area2 = (trbx - tltx) * (trby - tlty);

        // pred box 0: ch 0..4, pred box 1: ch 5..9
        const float b0x = p01.x, b0y = p01.y, b0w = p23.x, b0h = p23.y;
        const float b1x = p45.y, b1y = p67.x, b1w = p67.y, b1h = p89.x;

        float iou0, iou1;
        {
            const float pltx = b0x - 0.5f * b0w, plty = b0y - 0.5f * b0h;
            const float prbx = b0x + 0.5f * b0w, prby = b0y + 0.5f * b0h;
            const float ltx = fmaxf(pltx, tltx), lty = fmaxf(plty, tlty);
            const float rbx = fminf(prbx, trbx), rby = fminf(prby, trby);
            const float inter = ((rbx - ltx < 0.0f) ? 1.0f : 0.0f) *
                                ((rby - lty < 0.0f) ? 1.0f : 0.0f);
            const float area1 = (prbx - pltx) * (prby - plty);
            iou0 = inter / (area1 + area2 - inter);
        }
        {
            const float pltx = b1x - 0.5f * b1w, plty = b1y - 0.5f * b1h;
            const float prbx = b1x + 0.5f * b1w, prby = b1y + 0.5f * b1h;
            const float ltx = fmaxf(pltx, tltx), lty = fmaxf(plty, tlty);
            const float rbx = fminf(prbx, trbx), rby = fminf(prby, trby);
            const float inter = ((rbx - ltx < 0.0f) ? 1.0f : 0.0f) *
                                ((rby - lty < 0.0f) ? 1.0f : 0.0f);
            const float area1 = (prbx - pltx) * (prby - plty);
            iou1 = inter / (area1 + area2 - inter);
        }
        // jnp.argmax first-index tie-break: idx=1 only if strictly greater
        const bool idx1 = iou1 > iou0;

        const float rpx = idx1 ? b1x : b0x;
        const float rpy = idx1 ? b1y : b0y;
        const float rpw = idx1 ? b1w : b0w;
        const float rph = idx1 ? b1h : b0h;
        const float rpc = idx1 ? p89.y : p45.x;
        const float rtx = idx1 ? t45.y : t01.x;
        const float rty = idx1 ? t67.x : t01.y;
        const float rtw = idx1 ? t67.y : t23.x;
        const float rth = idx1 ? t89.x : t23.y;
        const float rtc = idx1 ? t89.y : t45.x;

        // contain loss (weight 1)
        const float dc = rpc - rtc;
        sum += dc * dc;

        // localization loss (weight 5)
        const float dx = rpx - rtx;
        const float dy = rpy - rty;
        const float dw = sqrtf(rpw) - sqrtf(rtw);
        const float dh = sqrtf(rph) - sqrtf(rth);
        sum += 5.0f * (dx * dx + dy * dy + dw * dw + dh * dh);
    }
    return sum;
}

__global__ __launch_bounds__(256, 3)
void yolo_partial(const float* __restrict__ pred,
                  const float* __restrict__ targ,
                  float* __restrict__ partial) {
    __shared__ float wave_sums[4];

    const int tid = threadIdx.x;
    const long long gid = (long long)blockIdx.x * 256 + tid;   // 0..196607
    const bool extra = gid < (N_CELLS - 4 * (long long)LANES_TOTAL);  // first 16384

    Cell A, B;
    float sum = 0.0f;

    // stage 0: fill A
    load_cell(A, targ, pred, gid);
    SCHED_FENCE();
    // stage 1 loads issued BEFORE stage 0 consumed (pinned by fences)
    load_cell(B, targ, pred, gid + LANES_TOTAL);
    SCHED_FENCE();
    sum += cell_loss(A);
    load_cell(A, targ, pred, gid + 2LL * LANES_TOTAL);
    SCHED_FENCE();
    sum += cell_loss(B);
    load_cell(B, targ, pred, gid + 3LL * LANES_TOTAL);
    SCHED_FENCE();
    sum += cell_loss(A);
    if (extra) load_cell(A, targ, pred, gid + 4LL * LANES_TOTAL);
    SCHED_FENCE();
    sum += cell_loss(B);
    if (extra) sum += cell_loss(A);

    // wave shuffle reduce, then block reduce
#pragma unroll
    for (int off = 32; off > 0; off >>= 1)
        sum += __shfl_down(sum, off, 64);
    const int wave = tid >> 6;
    const int lane = tid & 63;
    if (lane == 0) wave_sums[wave] = sum;
    __syncthreads();
    if (tid == 0) {
        partial[blockIdx.x] = (wave_sums[0] + wave_sums[1]) +
                              (wave_sums[2] + wave_sums[3]);
    }
}

__global__ __launch_bounds__(256)
void yolo_reduce(const float* __restrict__ partial, int n, float* __restrict__ out) {
    __shared__ float wave_sums[4];
    float s = 0.0f;
    const int n4 = n >> 2;
    const float4* p4 = (const float4*)partial;
    for (int v = threadIdx.x; v < n4; v += 256) {
        const float4 x = p4[v];
        s += (x.x + x.y) + (x.z + x.w);
    }
    for (int v = (n4 << 2) + threadIdx.x; v < n; v += 256)
        s += partial[v];
#pragma unroll
    for (int off = 32; off > 0; off >>= 1)
        s += __shfl_down(s, off, 64);
    const int wave = threadIdx.x >> 6;
    const int lane = threadIdx.x & 63;
    if (lane == 0) wave_sums[wave] = s;
    __syncthreads();
    if (threadIdx.x == 0) {
        const float tot = wave_sums[0] + wave_sums[1] + wave_sums[2] + wave_sums[3];
        out[0] = tot * (1.0f / 16384.0f);
    }
}

extern "C" void kernel_launch(void* const* d_in, const int* in_sizes, int n_in,
                              void* d_out, int out_size, void* d_ws, size_t ws_size,
                              hipStream_t stream) {
    const float* pred = (const float*)d_in[0];
    const float* targ = (const float*)d_in[1];
    float* out = (float*)d_out;
    float* partial = (float*)d_ws;

    const int blocks = LANES_TOTAL / 256;   // 768 = 3 resident blocks per CU

    yolo_partial<<<blocks, 256, 0, stream>>>(pred, targ, partial);
    yolo_reduce<<<1, 256, 0, stream>>>(partial, blocks, out);
}